// Round 11
// baseline (796.161 us; speedup 1.0000x reference)
//
#include <hip/hip_runtime.h>
#include <stdint.h>

#define NE 131072

typedef __attribute__((ext_vector_type(8))) short bf16x8;
typedef __attribute__((ext_vector_type(4))) float f32x4;

static __device__ __forceinline__ unsigned short f2bf(float f) {
  unsigned u = __float_as_uint(f);
  u += 0x7FFF + ((u >> 16) & 1);   // round-to-nearest-even
  return (unsigned short)(u >> 16);
}
static __device__ __forceinline__ float bf2f(unsigned short h) {
  return __uint_as_float((unsigned)h << 16);
}
static __device__ __forceinline__ void gload_lds16(const void* g, void* l) {
  __builtin_amdgcn_global_load_lds(
      (const __attribute__((address_space(1))) unsigned*)g,
      (__attribute__((address_space(3))) unsigned*)l, 16, 0, 0);
}

// Fused weight prep (verified R4-R10): dst[n][k] = bf16(src[k][n])
__global__ void weight_prep(const float* __restrict__ W0, const float* __restrict__ W1,
                            const float* __restrict__ W2, const float* __restrict__ SW0,
                            const float* __restrict__ SW1, const float* __restrict__ SW2,
                            unsigned short* W0t, unsigned short* W1t,
                            unsigned short* W2t, unsigned short* SW0t,
                            unsigned short* SW1t, unsigned short* SW2b) {
  __shared__ float tile[32][33];
  const int u = blockIdx.y;
  const float* src; unsigned short* dst; int K, Nc;
  if (u == 0)      { src = W0;  dst = W0t;  K = 64;  Nc = 512; }
  else if (u == 1) { src = W1;  dst = W1t;  K = 512; Nc = 512; }
  else if (u == 2) { src = W2;  dst = W2t;  K = 512; Nc = 512; }
  else if (u < 6)  { int p = u - 3; src = SW0 + (long)p * 512 * 512; dst = SW0t + (long)p * 512 * 512; K = 512; Nc = 512; }
  else if (u < 9)  { int p = u - 6; src = SW1 + (long)p * 512 * 256; dst = SW1t + (long)p * 256 * 512; K = 512; Nc = 256; }
  else             { int p = u - 9; src = SW2 + (long)p * 256;       dst = SW2b + (long)p * 256;       K = 256; Nc = 1; }
  const int tkn = K >> 5;
  const int tk = blockIdx.x % tkn, tn = blockIdx.x / tkn;
  if (tn >= ((Nc + 31) >> 5)) return;
  const int k0 = tk * 32, n0 = tn * 32;
  const int tx = threadIdx.x & 31, ty = threadIdx.x >> 5;
  if (n0 + tx < Nc)
#pragma unroll
    for (int j = 0; j < 4; ++j)
      tile[ty * 4 + j][tx] = src[(long)(k0 + ty * 4 + j) * Nc + n0 + tx];
  __syncthreads();
#pragma unroll
  for (int j = 0; j < 4; ++j) {
    int n = n0 + ty * 4 + j;
    if (n < Nc) dst[(long)n * K + k0 + tx] = f2bf(tile[tx][ty * 4 + j]);
  }
}

__global__ void relu_cvt_x(const float4* __restrict__ x,
                           ushort4* __restrict__ xb) {
  int i = blockIdx.x * blockDim.x + threadIdx.x;
  float4 v = x[i];
  ushort4 o;
  o.x = f2bf(fmaxf(v.x, 0.f));
  o.y = f2bf(fmaxf(v.y, 0.f));
  o.z = f2bf(fmaxf(v.z, 0.f));
  o.w = f2bf(fmaxf(v.w, 0.f));
  xb[i] = o;
}

// gemmS: m97 geometry + R9 counted-vmcnt 3-ring.
// BM=128 x BN=128, BK=32, 4 waves (2M x 2N), wave-tile 64x64 (8 ds_read per
// 16 MFMA — square-optimal). 3-deep ring of 16KB buffers (48KB LDS ->
// 3 blocks/CU, 12 waves/CU). Gate vmcnt(4) (tile t landed, t+1 in flight);
// one barrier per K-step. R6-R9-verified involution addressing (0 conflicts,
// coalesced). Grouped over blockIdx.z. Optional fused head partial (w2).
__global__ __launch_bounds__(256, 3) void gemmS(
    const unsigned short* __restrict__ A, long aZ,
    const unsigned short* __restrict__ Bt, long bZ,
    const float* __restrict__ bias, long biasZ,
    float* __restrict__ outF,
    unsigned short* __restrict__ outA, long cZ,
    int K, int Nc,
    const unsigned short* __restrict__ w2, long w2Z,
    float* __restrict__ PB, long pbZ, int r0) {
  __shared__ unsigned short lds[3 * 8192];   // 48 KB: per buf A 512 + B 512 chunks
  __shared__ float part[2][128];             // head partials
  const int z = blockIdx.z;
  A += (long)z * aZ;
  Bt += (long)z * bZ;
  bias += (long)z * biasZ;
  if (outA) outA += (long)z * cZ;
  if (w2) { w2 += (long)z * w2Z; PB += (long)z * pbZ; }

  const int tid = threadIdx.x, wave = tid >> 6, lane = tid & 63;
  const int wm = wave >> 1, wn = wave & 1;
  const int lr = lane & 15, lh = lane >> 4;
  const long brow = (long)blockIdx.x * 128;
  const int bcol = blockIdx.y * 128;
  const int nk = K >> 5;
  // read-side involution constant (elems): slot = lh ^ ((lr>>1)&3)
  const int axr = (lh ^ ((lr >> 1) & 3)) * 8;

  f32x4 acc[4][4];
#pragma unroll
  for (int m = 0; m < 4; ++m)
#pragma unroll
    for (int n = 0; n < 4; ++n) acc[m][n] = (f32x4){0.f, 0.f, 0.f, 0.f};

  // 4 loads/thread per tile (2 A + 2 B)
  auto STAGE = [&](int t) {
    if (t >= nk) return;
    unsigned short* dst = &lds[(t % 3) * 8192];
    const int k0 = t << 5;
#pragma unroll
    for (int i = 0; i < 2; ++i) {               // A: 512 chunks
      const int cb = i * 256 + wave * 64;
      const int c = cb + lane;
      const int r = c >> 2;
      const int kc = (c & 3) ^ ((r >> 1) & 3);
      gload_lds16(A + (brow + r) * (long)K + k0 + kc * 8, &dst[cb * 8]);
    }
#pragma unroll
    for (int i = 0; i < 2; ++i) {               // B: 512 chunks
      const int cb = i * 256 + wave * 64;
      const int c = cb + lane;
      const int r = c >> 2;
      const int kc = (c & 3) ^ ((r >> 1) & 3);
      gload_lds16(Bt + (long)(bcol + r) * K + k0 + kc * 8,
                  &dst[(512 + cb) * 8]);
    }
  };

  STAGE(0);
  STAGE(1);

  for (int t = 0; t < nk; ++t) {
    if (t < nk - 1)
      asm volatile("s_waitcnt vmcnt(4)" ::: "memory");
    else
      asm volatile("s_waitcnt vmcnt(0)" ::: "memory");
    __builtin_amdgcn_s_barrier();
    __builtin_amdgcn_sched_barrier(0);
    const unsigned short* buf = &lds[(t % 3) * 8192];
    bf16x8 a[4], b[4];
#pragma unroll
    for (int m = 0; m < 4; ++m)
      a[m] = *(const bf16x8*)&buf[(wm * 64 + m * 16 + lr) * 32 + axr];
#pragma unroll
    for (int n = 0; n < 4; ++n)
      b[n] = *(const bf16x8*)&buf[512 * 8 + (wn * 64 + n * 16 + lr) * 32 + axr];
    STAGE(t + 2);
    __builtin_amdgcn_s_setprio(1);
#pragma unroll
    for (int m = 0; m < 4; ++m)
#pragma unroll
      for (int n = 0; n < 4; ++n)
        acc[m][n] =
            __builtin_amdgcn_mfma_f32_16x16x32_bf16(a[m], b[n], acc[m][n], 0, 0, 0);
    __builtin_amdgcn_s_setprio(0);
  }

  float bv[4];
#pragma unroll
  for (int n = 0; n < 4; ++n) bv[n] = bias[bcol + wn * 64 + n * 16 + lr];

  if (!w2) {
#pragma unroll
    for (int m = 0; m < 4; ++m) {
#pragma unroll
      for (int r = 0; r < 4; ++r) {
        long e = brow + wm * 64 + m * 16 + lh * 4 + r;
#pragma unroll
        for (int n = 0; n < 4; ++n) {
          int oc = bcol + wn * 64 + n * 16 + lr;
          float v = acc[m][n][r] + bv[n];
          if (outF) outF[e * Nc + oc] = v;
          if (outA) outA[e * Nc + oc] = f2bf(fmaxf(v, 0.f));
        }
      }
    }
  } else {
    // fused head partial over this block's 128 cols: relu(h1+b) . w2
    float w2v[4];
#pragma unroll
    for (int n = 0; n < 4; ++n) w2v[n] = bf2f(w2[bcol + wn * 64 + n * 16 + lr]);
#pragma unroll
    for (int m = 0; m < 4; ++m) {
#pragma unroll
      for (int r = 0; r < 4; ++r) {
        float s = 0.f;
#pragma unroll
        for (int n = 0; n < 4; ++n)
          s += fmaxf(acc[m][n][r] + bv[n], 0.f) * w2v[n];
#pragma unroll
        for (int off = 1; off < 16; off <<= 1) s += __shfl_xor(s, off);
        if (lr == 0) part[wn][wm * 64 + m * 16 + lh * 4 + r] = s;
      }
    }
    __syncthreads();
    if (tid < 128)
      PB[(long)blockIdx.y * NE + r0 + brow + tid] =
          part[0][tid] + part[1][tid];
  }
}

__global__ void head_final(const float* __restrict__ PB,
                           const float* __restrict__ Sb2,
                           const int* __restrict__ y,
                           const int* __restrict__ pairs,
                           float* __restrict__ outR, float* __restrict__ outS,
                           float* __restrict__ outM) {
  const int n = blockIdx.x * 256 + threadIdx.x;
  const int p = blockIdx.y;
  float logit = PB[(long)p * 2 * NE + n] + PB[(long)(p * 2 + 1) * NE + n] +
                Sb2[p];
  float s = 1.f / (1.f + expf(-logit));
  s = fmaxf(s, 1e-9f);
  float r = (1.f - s) / s;
  int yv = y[n];
  float mf = (yv == pairs[p * 2] || yv == pairs[p * 2 + 1]) ? 1.f : 0.f;
  outR[(long)p * NE + n] = r * mf;
  outS[(long)p * NE + n] = s * mf;
  outM[(long)p * NE + n] = mf;
}

extern "C" void kernel_launch(void* const* d_in, const int* in_sizes, int n_in,
                              void* d_out, int out_size, void* d_ws, size_t ws_size,
                              hipStream_t stream) {
  const float* x   = (const float*)d_in[0];
  const int*   y   = (const int*)d_in[1];
  const int*   prs = (const int*)d_in[2];
  const float* W0  = (const float*)d_in[3];
  const float* b0  = (const float*)d_in[4];
  const float* W1  = (const float*)d_in[5];
  const float* b1  = (const float*)d_in[6];
  const float* W2  = (const float*)d_in[7];
  const float* b2  = (const float*)d_in[8];
  const float* SW0 = (const float*)d_in[9];
  const float* Sb0 = (const float*)d_in[10];
  const float* SW1 = (const float*)d_in[11];
  const float* Sb1 = (const float*)d_in[12];
  const float* SW2 = (const float*)d_in[13];
  const float* Sb2 = (const float*)d_in[14];

  uint8_t* ws = (uint8_t*)d_ws;
  size_t off = 0;
  auto take = [&](size_t bytes) -> void* {
    void* ptr = ws + off;
    off = (off + bytes + 255) & ~(size_t)255;
    return ptr;
  };
  unsigned short* W0t  = (unsigned short*)take((size_t)64 * 512 * 2);
  unsigned short* W1t  = (unsigned short*)take((size_t)512 * 512 * 2);
  unsigned short* W2t  = (unsigned short*)take((size_t)512 * 512 * 2);
  unsigned short* SW0t = (unsigned short*)take((size_t)3 * 512 * 512 * 2);
  unsigned short* SW1t = (unsigned short*)take((size_t)3 * 256 * 512 * 2);
  unsigned short* SW2b = (unsigned short*)take((size_t)3 * 256 * 2);
  unsigned short* Xb   = (unsigned short*)take((size_t)NE * 64 * 2);
  float*          PB   = (float*)take((size_t)6 * NE * 4);
  const size_t fixed = off;

  // Chunk capped at 32768 rows: producer->consumer set stays L3-resident
  // (R6 lesson: chunk=NE -> 134MB buffers -> L3 thrash -> HBM-bound).
  long chunk = 32768;
  while (chunk > 8192 && fixed + (size_t)6 * chunk * 1024 + 4096 > ws_size)
    chunk >>= 1;

  unsigned short* T0   = (unsigned short*)take((size_t)chunk * 512 * 2);
  unsigned short* T1   = (unsigned short*)take((size_t)chunk * 512 * 2);
  unsigned short* bufR = (unsigned short*)take((size_t)chunk * 512 * 2);
  unsigned short* H3   = (unsigned short*)take((size_t)3 * chunk * 512 * 2);

  float* out   = (float*)d_out;
  float* outRe = out;
  float* outR  = out + (size_t)NE * 512;
  float* outS  = outR + (size_t)3 * NE;
  float* outM  = outS + (size_t)3 * NE;

  weight_prep<<<dim3(256, 12), 256, 0, stream>>>(W0, W1, W2, SW0, SW1, SW2,
                                                 W0t, W1t, W2t, SW0t, SW1t, SW2b);
  relu_cvt_x<<<dim3(NE * 64 / 4 / 256), 256, 0, stream>>>((const float4*)x,
                                                          (ushort4*)Xb);

  for (long r0 = 0; r0 < NE; r0 += chunk) {
    // trunk: Xb -> T0 -> T1 -> (repr fp32, bufR bf16)
    gemmS<<<dim3(chunk / 128, 4, 1), 256, 0, stream>>>(
        Xb + r0 * 64, 0, W0t, 0, b0, 0, nullptr, T0, 0, 64, 512,
        nullptr, 0, nullptr, 0, 0);
    gemmS<<<dim3(chunk / 128, 4, 1), 256, 0, stream>>>(
        T0, 0, W1t, 0, b1, 0, nullptr, T1, 0, 512, 512,
        nullptr, 0, nullptr, 0, 0);
    gemmS<<<dim3(chunk / 128, 4, 1), 256, 0, stream>>>(
        T1, 0, W2t, 0, b2, 0, outRe + r0 * 512, bufR, 0, 512, 512,
        nullptr, 0, nullptr, 0, 0);
    // SW0 batched over p: bufR -> H3[p]
    gemmS<<<dim3(chunk / 128, 4, 3), 256, 0, stream>>>(
        bufR, 0, SW0t, (long)512 * 512, Sb0, 512, nullptr,
        H3, (long)chunk * 512, 512, 512,
        nullptr, 0, nullptr, 0, 0);
    // SW1 + head partials, batched over p
    gemmS<<<dim3(chunk / 128, 2, 3), 256, 0, stream>>>(
        H3, (long)chunk * 512, SW1t, (long)256 * 512, Sb1, 256, nullptr,
        nullptr, 0, 512, 256,
        SW2b, 256, PB, (long)2 * NE, (int)r0);
  }
  head_final<<<dim3(NE / 256, 3), 256, 0, stream>>>(PB, Sb2, y, prs,
                                                    outR, outS, outM);
}

// Round 12
// 718.043 us; speedup vs baseline: 1.1088x; 1.1088x over previous
//
#include <hip/hip_runtime.h>
#include <stdint.h>

#define NE 131072

typedef __attribute__((ext_vector_type(8))) short bf16x8;
typedef __attribute__((ext_vector_type(4))) float f32x4;

static __device__ __forceinline__ unsigned short f2bf(float f) {
  unsigned u = __float_as_uint(f);
  u += 0x7FFF + ((u >> 16) & 1);   // round-to-nearest-even
  return (unsigned short)(u >> 16);
}
static __device__ __forceinline__ float bf2f(unsigned short h) {
  return __uint_as_float((unsigned)h << 16);
}
static __device__ __forceinline__ void gload_lds16(const void* g, void* l) {
  __builtin_amdgcn_global_load_lds(
      (const __attribute__((address_space(1))) unsigned*)g,
      (__attribute__((address_space(3))) unsigned*)l, 16, 0, 0);
}

// Fused weight prep (verified R4-R11): dst[n][k] = bf16(src[k][n])
__global__ void weight_prep(const float* __restrict__ W0, const float* __restrict__ W1,
                            const float* __restrict__ W2, const float* __restrict__ SW0,
                            const float* __restrict__ SW1, const float* __restrict__ SW2,
                            unsigned short* W0t, unsigned short* W1t,
                            unsigned short* W2t, unsigned short* SW0t,
                            unsigned short* SW1t, unsigned short* SW2b) {
  __shared__ float tile[32][33];
  const int u = blockIdx.y;
  const float* src; unsigned short* dst; int K, Nc;
  if (u == 0)      { src = W0;  dst = W0t;  K = 64;  Nc = 512; }
  else if (u == 1) { src = W1;  dst = W1t;  K = 512; Nc = 512; }
  else if (u == 2) { src = W2;  dst = W2t;  K = 512; Nc = 512; }
  else if (u < 6)  { int p = u - 3; src = SW0 + (long)p * 512 * 512; dst = SW0t + (long)p * 512 * 512; K = 512; Nc = 512; }
  else if (u < 9)  { int p = u - 6; src = SW1 + (long)p * 512 * 256; dst = SW1t + (long)p * 256 * 512; K = 512; Nc = 256; }
  else             { int p = u - 9; src = SW2 + (long)p * 256;       dst = SW2b + (long)p * 256;       K = 256; Nc = 1; }
  const int tkn = K >> 5;
  const int tk = blockIdx.x % tkn, tn = blockIdx.x / tkn;
  if (tn >= ((Nc + 31) >> 5)) return;
  const int k0 = tk * 32, n0 = tn * 32;
  const int tx = threadIdx.x & 31, ty = threadIdx.x >> 5;
  if (n0 + tx < Nc)
#pragma unroll
    for (int j = 0; j < 4; ++j)
      tile[ty * 4 + j][tx] = src[(long)(k0 + ty * 4 + j) * Nc + n0 + tx];
  __syncthreads();
#pragma unroll
  for (int j = 0; j < 4; ++j) {
    int n = n0 + ty * 4 + j;
    if (n < Nc) dst[(long)n * K + k0 + tx] = f2bf(tile[tx][ty * 4 + j]);
  }
}

__global__ void relu_cvt_x(const float4* __restrict__ x,
                           ushort4* __restrict__ xb) {
  int i = blockIdx.x * blockDim.x + threadIdx.x;
  float4 v = x[i];
  ushort4 o;
  o.x = f2bf(fmaxf(v.x, 0.f));
  o.y = f2bf(fmaxf(v.y, 0.f));
  o.z = f2bf(fmaxf(v.z, 0.f));
  o.w = f2bf(fmaxf(v.w, 0.f));
  xb[i] = o;
}

// Deterministic per-(chunk, pair) compaction of active rows (y in pair).
// idxL[p][cb + pos] = local row; posA[p][n] = global compact pos or -1;
// cnts[c*3+p] = count. Pads idxL to the next 256 multiple (dup last row).
__global__ void build_idx(const int* __restrict__ y, const int* __restrict__ pairs,
                          int chunkRows, int* __restrict__ idxL,
                          int* __restrict__ posA, int* __restrict__ cnts) {
  const int c = blockIdx.x, p = blockIdx.y;
  const int la = pairs[p * 2], lb = pairs[p * 2 + 1];
  const long r0 = (long)c * chunkRows;
  const long cb = r0;                      // compact base = c*chunk
  __shared__ int wbase[4];
  __shared__ int running;
  if (threadIdx.x == 0) running = 0;
  __syncthreads();
  const int lane = threadIdx.x & 63, wv = threadIdx.x >> 6;
  for (int it = 0; it < chunkRows / 256; ++it) {
    const int r = it * 256 + threadIdx.x;
    const int yv = y[r0 + r];
    const bool act = (yv == la) || (yv == lb);
    const unsigned long long m = __ballot(act);
    const int rank = __popcll(m & ((1ull << lane) - 1));
    if (lane == 0) wbase[wv] = __popcll(m);
    __syncthreads();
    int wb = 0;
#pragma unroll
    for (int w = 0; w < 4; ++w) wb += (w < wv) ? wbase[w] : 0;
    const int tot = wbase[0] + wbase[1] + wbase[2] + wbase[3];
    if (act) {
      const int posi = running + wb + rank;
      idxL[(long)p * NE + cb + posi] = r;
      posA[(long)p * NE + r0 + r] = (int)(cb + posi);
    } else {
      posA[(long)p * NE + r0 + r] = -1;
    }
    __syncthreads();
    if (threadIdx.x == 0) running += tot;
    __syncthreads();
  }
  const int cnt = running;
  if (threadIdx.x == 0) cnts[c * 3 + p] = cnt;
  const int padded = (cnt + 255) & ~255;
  const int last = (cnt > 0) ? idxL[(long)p * NE + cb + cnt - 1] : 0;
  for (int i = cnt + threadIdx.x; i < padded; i += 256)
    idxL[(long)p * NE + cb + i] = last;
}

// gemmP (R9-verified): BM=256 x BN=128, BK=32, 8 waves, 3-ring 72KB,
// 2 blocks/CU, counted vmcnt(3) gate, involution addressing (0 conflicts).
// NEW: optional A-row gather (aIdx, hoisted to 2 pre-loop loads — row per
// thread is K-tile-invariant) and block-uniform early-exit on cnts.
__global__ __launch_bounds__(512, 4) void gemmP(
    const unsigned short* __restrict__ A, long aZ,
    const unsigned short* __restrict__ Bt, long bZ,
    const float* __restrict__ bias, long biasZ,
    float* __restrict__ outF,
    unsigned short* __restrict__ outA, long cZ,
    int K, int Nc,
    const unsigned short* __restrict__ w2, long w2Z,
    float* __restrict__ PB, long pbZ, int r0,
    const int* __restrict__ aIdx, long aIdxZ,
    const int* __restrict__ cnts) {
  __shared__ unsigned short lds[3 * 12288];
  __shared__ float part[4][256];
  const int z = blockIdx.z;
  const long brow = (long)blockIdx.x * 256;
  if (cnts) {                              // compact-count early exit
    const int cp = cnts[z];
    if ((int)brow >= ((cp + 255) & ~255)) return;
  }
  A += (long)z * aZ;
  Bt += (long)z * bZ;
  bias += (long)z * biasZ;
  if (outA) outA += (long)z * cZ;
  if (w2) { w2 += (long)z * w2Z; PB += (long)z * pbZ; }
  if (aIdx) aIdx += (long)z * aIdxZ;

  const int tid = threadIdx.x, wave = tid >> 6, lane = tid & 63;
  const int wm = wave >> 2, wn = wave & 3;
  const int lr = lane & 15, lh = lane >> 4;
  const int bcol = blockIdx.y * 128;
  const int nk = K >> 5;
  const int axr = (lh ^ ((lr >> 1) & 3)) * 8;

  // A source rows (K-tile-invariant): gather through aIdx if present
  int arow[2];
#pragma unroll
  for (int i = 0; i < 2; ++i) {
    const int c = i * 512 + wave * 64 + lane;
    const int r = c >> 2;
    arow[i] = aIdx ? aIdx[brow + r] : (int)(brow + r);
  }

  f32x4 acc[8][2];
#pragma unroll
  for (int m = 0; m < 8; ++m)
#pragma unroll
    for (int n = 0; n < 2; ++n) acc[m][n] = (f32x4){0.f, 0.f, 0.f, 0.f};

  auto STAGE = [&](int t) {
    if (t >= nk) return;
    unsigned short* dst = &lds[(t % 3) * 12288];
    const int k0 = t << 5;
#pragma unroll
    for (int i = 0; i < 2; ++i) {
      const int cb = i * 512 + wave * 64;
      const int c = cb + lane;
      const int r = c >> 2;                      // LDS-local row (keys kc)
      const int kc = (c & 3) ^ ((r >> 1) & 3);
      gload_lds16(A + (long)arow[i] * K + k0 + kc * 8, &dst[cb * 8]);
    }
    {
      const int cb = wave * 64;
      const int c = cb + lane;
      const int r = c >> 2;
      const int kc = (c & 3) ^ ((r >> 1) & 3);
      gload_lds16(Bt + (long)(bcol + r) * K + k0 + kc * 8,
                  &dst[(1024 + cb) * 8]);
    }
  };

  STAGE(0);
  STAGE(1);

  for (int t = 0; t < nk; ++t) {
    if (t < nk - 1)
      asm volatile("s_waitcnt vmcnt(3)" ::: "memory");
    else
      asm volatile("s_waitcnt vmcnt(0)" ::: "memory");
    __builtin_amdgcn_s_barrier();
    __builtin_amdgcn_sched_barrier(0);
    const unsigned short* buf = &lds[(t % 3) * 12288];
    bf16x8 a[8], b[2];
#pragma unroll
    for (int m = 0; m < 8; ++m)
      a[m] = *(const bf16x8*)&buf[(wm * 128 + m * 16 + lr) * 32 + axr];
#pragma unroll
    for (int n = 0; n < 2; ++n)
      b[n] = *(const bf16x8*)&buf[1024 * 8 + (wn * 32 + n * 16 + lr) * 32 + axr];
    STAGE(t + 2);
    __builtin_amdgcn_s_setprio(1);
#pragma unroll
    for (int m = 0; m < 8; ++m)
#pragma unroll
      for (int n = 0; n < 2; ++n)
        acc[m][n] =
            __builtin_amdgcn_mfma_f32_16x16x32_bf16(a[m], b[n], acc[m][n], 0, 0, 0);
    __builtin_amdgcn_s_setprio(0);
  }

  float bv[2];
#pragma unroll
  for (int n = 0; n < 2; ++n) bv[n] = bias[bcol + wn * 32 + n * 16 + lr];

  if (!w2) {
#pragma unroll
    for (int m = 0; m < 8; ++m) {
#pragma unroll
      for (int r = 0; r < 4; ++r) {
        long e = brow + wm * 128 + m * 16 + lh * 4 + r;
#pragma unroll
        for (int n = 0; n < 2; ++n) {
          int oc = bcol + wn * 32 + n * 16 + lr;
          float v = acc[m][n][r] + bv[n];
          if (outF) outF[e * Nc + oc] = v;
          if (outA) outA[e * Nc + oc] = f2bf(fmaxf(v, 0.f));
        }
      }
    }
  } else {
    // fused head partial over this block's 128 cols: relu(h1+b) . w2
    float w2v[2];
#pragma unroll
    for (int n = 0; n < 2; ++n) w2v[n] = bf2f(w2[bcol + wn * 32 + n * 16 + lr]);
#pragma unroll
    for (int m = 0; m < 8; ++m) {
#pragma unroll
      for (int r = 0; r < 4; ++r) {
        float s = 0.f;
#pragma unroll
        for (int n = 0; n < 2; ++n)
          s += fmaxf(acc[m][n][r] + bv[n], 0.f) * w2v[n];
#pragma unroll
        for (int off = 1; off < 16; off <<= 1) s += __shfl_xor(s, off);
        if (lr == 0) part[wn][wm * 128 + m * 16 + lh * 4 + r] = s;
      }
    }
    __syncthreads();
    if (tid < 256)
      PB[(long)blockIdx.y * NE + r0 + brow + tid] =
          part[0][tid] + part[1][tid] + part[2][tid] + part[3][tid];
  }
}

// Scatter head: compact PB -> dense outputs via posA; zeros for masked.
__global__ void head_final(const float* __restrict__ PB,
                           const int* __restrict__ posA,
                           const float* __restrict__ Sb2,
                           float* __restrict__ outR, float* __restrict__ outS,
                           float* __restrict__ outM) {
  const long n = (long)blockIdx.x * 256 + threadIdx.x;
  const int p = blockIdx.y;
  const int pos = posA[(long)p * NE + n];
  float rr = 0.f, s = 0.f, mf = 0.f;
  if (pos >= 0) {
    float logit = PB[(long)p * 2 * NE + pos] + PB[((long)p * 2 + 1) * NE + pos] +
                  Sb2[p];
    s = 1.f / (1.f + expf(-logit));
    s = fmaxf(s, 1e-9f);
    rr = (1.f - s) / s;
    mf = 1.f;
  }
  outR[(long)p * NE + n] = rr;
  outS[(long)p * NE + n] = s;
  outM[(long)p * NE + n] = mf;
}

extern "C" void kernel_launch(void* const* d_in, const int* in_sizes, int n_in,
                              void* d_out, int out_size, void* d_ws, size_t ws_size,
                              hipStream_t stream) {
  const float* x   = (const float*)d_in[0];
  const int*   y   = (const int*)d_in[1];
  const int*   prs = (const int*)d_in[2];
  const float* W0  = (const float*)d_in[3];
  const float* b0  = (const float*)d_in[4];
  const float* W1  = (const float*)d_in[5];
  const float* b1  = (const float*)d_in[6];
  const float* W2  = (const float*)d_in[7];
  const float* b2  = (const float*)d_in[8];
  const float* SW0 = (const float*)d_in[9];
  const float* Sb0 = (const float*)d_in[10];
  const float* SW1 = (const float*)d_in[11];
  const float* Sb1 = (const float*)d_in[12];
  const float* SW2 = (const float*)d_in[13];
  const float* Sb2 = (const float*)d_in[14];

  uint8_t* ws = (uint8_t*)d_ws;
  size_t off = 0;
  auto take = [&](size_t bytes) -> void* {
    void* ptr = ws + off;
    off = (off + bytes + 255) & ~(size_t)255;
    return ptr;
  };
  unsigned short* W0t  = (unsigned short*)take((size_t)64 * 512 * 2);
  unsigned short* W1t  = (unsigned short*)take((size_t)512 * 512 * 2);
  unsigned short* W2t  = (unsigned short*)take((size_t)512 * 512 * 2);
  unsigned short* SW0t = (unsigned short*)take((size_t)3 * 512 * 512 * 2);
  unsigned short* SW1t = (unsigned short*)take((size_t)3 * 256 * 512 * 2);
  unsigned short* SW2b = (unsigned short*)take((size_t)3 * 256 * 2);
  unsigned short* Xb   = (unsigned short*)take((size_t)NE * 64 * 2);
  float*          PB   = (float*)take((size_t)6 * NE * 4);
  int*            idxL = (int*)take((size_t)3 * NE * 4);
  int*            posA = (int*)take((size_t)3 * NE * 4);
  int*            cnts = (int*)take((size_t)64 * 4);
  const size_t fixed = off;

  // Chunk capped at 32768 rows: producer->consumer set stays L3-resident
  // (R6 lesson: chunk=NE -> 134MB buffers -> L3 thrash -> HBM-bound).
  long chunk = 32768;
  while (chunk > 8192 && fixed + (size_t)6 * chunk * 1024 + 4096 > ws_size)
    chunk >>= 1;
  const int nchunks = (int)(NE / chunk);

  unsigned short* T0   = (unsigned short*)take((size_t)chunk * 512 * 2);
  unsigned short* T1   = (unsigned short*)take((size_t)chunk * 512 * 2);
  unsigned short* bufR = (unsigned short*)take((size_t)chunk * 512 * 2);
  unsigned short* H3   = (unsigned short*)take((size_t)3 * chunk * 512 * 2);

  float* out   = (float*)d_out;
  float* outRe = out;
  float* outR  = out + (size_t)NE * 512;
  float* outS  = outR + (size_t)3 * NE;
  float* outM  = outS + (size_t)3 * NE;

  weight_prep<<<dim3(256, 12), 256, 0, stream>>>(W0, W1, W2, SW0, SW1, SW2,
                                                 W0t, W1t, W2t, SW0t, SW1t, SW2b);
  relu_cvt_x<<<dim3(NE * 64 / 4 / 256), 256, 0, stream>>>((const float4*)x,
                                                          (ushort4*)Xb);
  build_idx<<<dim3(nchunks, 3), 256, 0, stream>>>(y, prs, (int)chunk,
                                                  idxL, posA, cnts);

  for (int c = 0; c < nchunks; ++c) {
    const long r0 = (long)c * chunk;
    // trunk: Xb -> T0 -> T1 -> (repr fp32, bufR bf16)
    gemmP<<<dim3(chunk / 256, 4, 1), 512, 0, stream>>>(
        Xb + r0 * 64, 0, W0t, 0, b0, 0, nullptr, T0, 0, 64, 512,
        nullptr, 0, nullptr, 0, 0, nullptr, 0, nullptr);
    gemmP<<<dim3(chunk / 256, 4, 1), 512, 0, stream>>>(
        T0, 0, W1t, 0, b1, 0, nullptr, T1, 0, 512, 512,
        nullptr, 0, nullptr, 0, 0, nullptr, 0, nullptr);
    gemmP<<<dim3(chunk / 256, 4, 1), 512, 0, stream>>>(
        T1, 0, W2t, 0, b2, 0, outRe + r0 * 512, bufR, 0, 512, 512,
        nullptr, 0, nullptr, 0, 0, nullptr, 0, nullptr);
    // SW0 batched over p, COMPACTED rows via idx gather: bufR -> H3[p]
    gemmP<<<dim3(chunk / 256, 4, 3), 512, 0, stream>>>(
        bufR, 0, SW0t, (long)512 * 512, Sb0, 512, nullptr,
        H3, (long)chunk * 512, 512, 512,
        nullptr, 0, nullptr, 0, 0, idxL + r0, NE, cnts + c * 3);
    // SW1 + head partials on compact rows, batched over p
    gemmP<<<dim3(chunk / 256, 2, 3), 512, 0, stream>>>(
        H3, (long)chunk * 512, SW1t, (long)256 * 512, Sb1, 256, nullptr,
        nullptr, 0, 512, 256,
        SW2b, 256, PB, (long)2 * NE, (int)r0, nullptr, 0, cnts + c * 3);
  }
  head_final<<<dim3(NE / 256, 3), 256, 0, stream>>>(PB, posA, Sb2,
                                                    outR, outS, outM);
}

// Round 13
// 696.006 us; speedup vs baseline: 1.1439x; 1.0317x over previous
//
#include <hip/hip_runtime.h>
#include <stdint.h>

#define NE 131072

typedef __attribute__((ext_vector_type(8))) short bf16x8;
typedef __attribute__((ext_vector_type(4))) float f32x4;

static __device__ __forceinline__ unsigned short f2bf(float f) {
  unsigned u = __float_as_uint(f);
  u += 0x7FFF + ((u >> 16) & 1);   // round-to-nearest-even
  return (unsigned short)(u >> 16);
}
static __device__ __forceinline__ float bf2f(unsigned short h) {
  return __uint_as_float((unsigned)h << 16);
}
static __device__ __forceinline__ void gload_lds16(const void* g, void* l) {
  __builtin_amdgcn_global_load_lds(
      (const __attribute__((address_space(1))) unsigned*)g,
      (__attribute__((address_space(3))) unsigned*)l, 16, 0, 0);
}

// Fused weight prep (verified R4-R12): dst[n][k] = bf16(src[k][n])
__global__ void weight_prep(const float* __restrict__ W0, const float* __restrict__ W1,
                            const float* __restrict__ W2, const float* __restrict__ SW0,
                            const float* __restrict__ SW1, const float* __restrict__ SW2,
                            unsigned short* W0t, unsigned short* W1t,
                            unsigned short* W2t, unsigned short* SW0t,
                            unsigned short* SW1t, unsigned short* SW2b) {
  __shared__ float tile[32][33];
  const int u = blockIdx.y;
  const float* src; unsigned short* dst; int K, Nc;
  if (u == 0)      { src = W0;  dst = W0t;  K = 64;  Nc = 512; }
  else if (u == 1) { src = W1;  dst = W1t;  K = 512; Nc = 512; }
  else if (u == 2) { src = W2;  dst = W2t;  K = 512; Nc = 512; }
  else if (u < 6)  { int p = u - 3; src = SW0 + (long)p * 512 * 512; dst = SW0t + (long)p * 512 * 512; K = 512; Nc = 512; }
  else if (u < 9)  { int p = u - 6; src = SW1 + (long)p * 512 * 256; dst = SW1t + (long)p * 256 * 512; K = 512; Nc = 256; }
  else             { int p = u - 9; src = SW2 + (long)p * 256;       dst = SW2b + (long)p * 256;       K = 256; Nc = 1; }
  const int tkn = K >> 5;
  const int tk = blockIdx.x % tkn, tn = blockIdx.x / tkn;
  if (tn >= ((Nc + 31) >> 5)) return;
  const int k0 = tk * 32, n0 = tn * 32;
  const int tx = threadIdx.x & 31, ty = threadIdx.x >> 5;
  if (n0 + tx < Nc)
#pragma unroll
    for (int j = 0; j < 4; ++j)
      tile[ty * 4 + j][tx] = src[(long)(k0 + ty * 4 + j) * Nc + n0 + tx];
  __syncthreads();
#pragma unroll
  for (int j = 0; j < 4; ++j) {
    int n = n0 + ty * 4 + j;
    if (n < Nc) dst[(long)n * K + k0 + tx] = f2bf(tile[tx][ty * 4 + j]);
  }
}

__global__ void relu_cvt_x(const float4* __restrict__ x,
                           ushort4* __restrict__ xb) {
  int i = blockIdx.x * blockDim.x + threadIdx.x;
  float4 v = x[i];
  ushort4 o;
  o.x = f2bf(fmaxf(v.x, 0.f));
  o.y = f2bf(fmaxf(v.y, 0.f));
  o.z = f2bf(fmaxf(v.z, 0.f));
  o.w = f2bf(fmaxf(v.w, 0.f));
  xb[i] = o;
}

// Deterministic per-(chunk, pair) compaction (verified R12).
__global__ void build_idx(const int* __restrict__ y, const int* __restrict__ pairs,
                          int chunkRows, int* __restrict__ idxL,
                          int* __restrict__ posA, int* __restrict__ cnts) {
  const int c = blockIdx.x, p = blockIdx.y;
  const int la = pairs[p * 2], lb = pairs[p * 2 + 1];
  const long r0 = (long)c * chunkRows;
  const long cb = r0;
  __shared__ int wbase[4];
  __shared__ int running;
  if (threadIdx.x == 0) running = 0;
  __syncthreads();
  const int lane = threadIdx.x & 63, wv = threadIdx.x >> 6;
  for (int it = 0; it < chunkRows / 256; ++it) {
    const int r = it * 256 + threadIdx.x;
    const int yv = y[r0 + r];
    const bool act = (yv == la) || (yv == lb);
    const unsigned long long m = __ballot(act);
    const int rank = __popcll(m & ((1ull << lane) - 1));
    if (lane == 0) wbase[wv] = __popcll(m);
    __syncthreads();
    int wb = 0;
#pragma unroll
    for (int w = 0; w < 4; ++w) wb += (w < wv) ? wbase[w] : 0;
    const int tot = wbase[0] + wbase[1] + wbase[2] + wbase[3];
    if (act) {
      const int posi = running + wb + rank;
      idxL[(long)p * NE + cb + posi] = r;
      posA[(long)p * NE + r0 + r] = (int)(cb + posi);
    } else {
      posA[(long)p * NE + r0 + r] = -1;
    }
    __syncthreads();
    if (threadIdx.x == 0) running += tot;
    __syncthreads();
  }
  const int cnt = running;
  if (threadIdx.x == 0) cnts[c * 3 + p] = cnt;
  const int padded = (cnt + 255) & ~255;
  const int last = (cnt > 0) ? idxL[(long)p * NE + cb + cnt - 1] : 0;
  for (int i = cnt + threadIdx.x; i < padded; i += 256)
    idxL[(long)p * NE + cb + i] = last;
}

// gemmT: R9 schedule (3-ring 72KB, 2 blk/CU, counted vmcnt(3), involution
// addressing) with BM=128 x BN=256 geometry: 8 waves 2M x 4N -> 64x64
// wave-tile (8 ds_read_b128 per 16 MFMA, vs gemmP's 10). y-tiles halve ->
// A-panel L3 re-reads halve. 3 loads/thread/tile (1 A + 2 B).
// Optional A-row gather (aIdx, K-invariant, hoisted) + early-exit (cnts).
// Optional fused full head (w2): Nc=256 fits one block -> complete logit.
__global__ __launch_bounds__(512, 4) void gemmT(
    const unsigned short* __restrict__ A, long aZ,
    const unsigned short* __restrict__ Bt, long bZ,
    const float* __restrict__ bias, long biasZ,
    float* __restrict__ outF,
    unsigned short* __restrict__ outA, long cZ,
    int K, int Nc,
    const unsigned short* __restrict__ w2, long w2Z,
    float* __restrict__ PB, long pbZ, int r0,
    const int* __restrict__ aIdx, long aIdxZ,
    const int* __restrict__ cnts) {
  __shared__ unsigned short lds[3 * 12288];   // 72 KB: per buf A 8KB + B 16KB
  __shared__ float part[4][128];
  const int z = blockIdx.z;
  const long brow = (long)blockIdx.x * 128;
  if (cnts) {
    const int cp = cnts[z];
    if ((int)brow >= ((cp + 255) & ~255)) return;
  }
  A += (long)z * aZ;
  Bt += (long)z * bZ;
  bias += (long)z * biasZ;
  if (outA) outA += (long)z * cZ;
  if (w2) { w2 += (long)z * w2Z; PB += (long)z * pbZ; }
  if (aIdx) aIdx += (long)z * aIdxZ;

  const int tid = threadIdx.x, wave = tid >> 6, lane = tid & 63;
  const int wm = wave >> 2, wn = wave & 3;   // 2M x 4N
  const int lr = lane & 15, lh = lane >> 4;
  const int bcol = blockIdx.y * 256;
  const int nk = K >> 5;
  const int axr = (lh ^ ((lr >> 1) & 3)) * 8;   // involution read col (elems)

  // A source row (K-tile-invariant; 1 stage-load/thread)
  const int arL = tid >> 2;                     // LDS-local A row 0..127
  const int arow = aIdx ? aIdx[brow + arL] : (int)(brow + arL);

  f32x4 acc[4][4];
#pragma unroll
  for (int m = 0; m < 4; ++m)
#pragma unroll
    for (int n = 0; n < 4; ++n) acc[m][n] = (f32x4){0.f, 0.f, 0.f, 0.f};

  auto STAGE = [&](int t) {
    if (t >= nk) return;
    unsigned short* dst = &lds[(t % 3) * 12288];
    const int k0 = t << 5;
    {                                           // A: 512 chunks, 1/thread
      const int c = tid;
      const int r = c >> 2;
      const int kc = (c & 3) ^ ((r >> 1) & 3);
      gload_lds16(A + (long)arow * K + k0 + kc * 8, &dst[(wave * 64) * 8]);
    }
#pragma unroll
    for (int i = 0; i < 2; ++i) {               // B: 1024 chunks, 2/thread
      const int cb = i * 512 + wave * 64;
      const int c = cb + lane;
      const int r = c >> 2;
      const int kc = (c & 3) ^ ((r >> 1) & 3);
      gload_lds16(Bt + (long)(bcol + r) * K + k0 + kc * 8,
                  &dst[(512 + cb) * 8]);
    }
  };

  STAGE(0);
  STAGE(1);

  for (int t = 0; t < nk; ++t) {
    if (t < nk - 1)
      asm volatile("s_waitcnt vmcnt(3)" ::: "memory");
    else
      asm volatile("s_waitcnt vmcnt(0)" ::: "memory");
    __builtin_amdgcn_s_barrier();
    __builtin_amdgcn_sched_barrier(0);
    const unsigned short* buf = &lds[(t % 3) * 12288];
    bf16x8 a[4], b[4];
#pragma unroll
    for (int m = 0; m < 4; ++m)
      a[m] = *(const bf16x8*)&buf[(wm * 64 + m * 16 + lr) * 32 + axr];
#pragma unroll
    for (int n = 0; n < 4; ++n)
      b[n] = *(const bf16x8*)&buf[512 * 8 + (wn * 64 + n * 16 + lr) * 32 + axr];
    STAGE(t + 2);
    __builtin_amdgcn_s_setprio(1);
#pragma unroll
    for (int m = 0; m < 4; ++m)
#pragma unroll
      for (int n = 0; n < 4; ++n)
        acc[m][n] =
            __builtin_amdgcn_mfma_f32_16x16x32_bf16(a[m], b[n], acc[m][n], 0, 0, 0);
    __builtin_amdgcn_s_setprio(0);
  }

  float bv[4];
#pragma unroll
  for (int n = 0; n < 4; ++n) bv[n] = bias[bcol + wn * 64 + n * 16 + lr];

  if (!w2) {
#pragma unroll
    for (int m = 0; m < 4; ++m) {
#pragma unroll
      for (int r = 0; r < 4; ++r) {
        long e = brow + wm * 64 + m * 16 + lh * 4 + r;
#pragma unroll
        for (int n = 0; n < 4; ++n) {
          int oc = bcol + wn * 64 + n * 16 + lr;
          float v = acc[m][n][r] + bv[n];
          if (outF) outF[e * Nc + oc] = v;
          if (outA) outA[e * Nc + oc] = f2bf(fmaxf(v, 0.f));
        }
      }
    }
  } else {
    // full fused head (Nc=256 in one block): logit partials per wn group
    float w2v[4];
#pragma unroll
    for (int n = 0; n < 4; ++n) w2v[n] = bf2f(w2[wn * 64 + n * 16 + lr]);
#pragma unroll
    for (int m = 0; m < 4; ++m) {
#pragma unroll
      for (int r = 0; r < 4; ++r) {
        float s = 0.f;
#pragma unroll
        for (int n = 0; n < 4; ++n)
          s += fmaxf(acc[m][n][r] + bv[n], 0.f) * w2v[n];
#pragma unroll
        for (int off = 1; off < 16; off <<= 1) s += __shfl_xor(s, off);
        if (lr == 0) part[wn][wm * 64 + m * 16 + lh * 4 + r] = s;
      }
    }
    __syncthreads();
    if (tid < 128)
      PB[r0 + brow + tid] =
          part[0][tid] + part[1][tid] + part[2][tid] + part[3][tid];
  }
}

// Scatter head: compact PB -> dense outputs via posA; zeros for masked.
__global__ void head_final(const float* __restrict__ PB,
                           const int* __restrict__ posA,
                           const float* __restrict__ Sb2,
                           float* __restrict__ outR, float* __restrict__ outS,
                           float* __restrict__ outM) {
  const long n = (long)blockIdx.x * 256 + threadIdx.x;
  const int p = blockIdx.y;
  const int pos = posA[(long)p * NE + n];
  float rr = 0.f, s = 0.f, mf = 0.f;
  if (pos >= 0) {
    float logit = PB[(long)p * NE + pos] + Sb2[p];
    s = 1.f / (1.f + expf(-logit));
    s = fmaxf(s, 1e-9f);
    rr = (1.f - s) / s;
    mf = 1.f;
  }
  outR[(long)p * NE + n] = rr;
  outS[(long)p * NE + n] = s;
  outM[(long)p * NE + n] = mf;
}

extern "C" void kernel_launch(void* const* d_in, const int* in_sizes, int n_in,
                              void* d_out, int out_size, void* d_ws, size_t ws_size,
                              hipStream_t stream) {
  const float* x   = (const float*)d_in[0];
  const int*   y   = (const int*)d_in[1];
  const int*   prs = (const int*)d_in[2];
  const float* W0  = (const float*)d_in[3];
  const float* b0  = (const float*)d_in[4];
  const float* W1  = (const float*)d_in[5];
  const float* b1  = (const float*)d_in[6];
  const float* W2  = (const float*)d_in[7];
  const float* b2  = (const float*)d_in[8];
  const float* SW0 = (const float*)d_in[9];
  const float* Sb0 = (const float*)d_in[10];
  const float* SW1 = (const float*)d_in[11];
  const float* Sb1 = (const float*)d_in[12];
  const float* SW2 = (const float*)d_in[13];
  const float* Sb2 = (const float*)d_in[14];

  uint8_t* ws = (uint8_t*)d_ws;
  size_t off = 0;
  auto take = [&](size_t bytes) -> void* {
    void* ptr = ws + off;
    off = (off + bytes + 255) & ~(size_t)255;
    return ptr;
  };
  unsigned short* W0t  = (unsigned short*)take((size_t)64 * 512 * 2);
  unsigned short* W1t  = (unsigned short*)take((size_t)512 * 512 * 2);
  unsigned short* W2t  = (unsigned short*)take((size_t)512 * 512 * 2);
  unsigned short* SW0t = (unsigned short*)take((size_t)3 * 512 * 512 * 2);
  unsigned short* SW1t = (unsigned short*)take((size_t)3 * 256 * 512 * 2);
  unsigned short* SW2b = (unsigned short*)take((size_t)3 * 256 * 2);
  unsigned short* Xb   = (unsigned short*)take((size_t)NE * 64 * 2);
  float*          PB   = (float*)take((size_t)3 * NE * 4);
  int*            idxL = (int*)take((size_t)3 * NE * 4);
  int*            posA = (int*)take((size_t)3 * NE * 4);
  int*            cnts = (int*)take((size_t)64 * 4);
  const size_t fixed = off;

  // Chunk capped at 32768 rows: producer->consumer set stays L3-resident.
  long chunk = 32768;
  while (chunk > 8192 && fixed + (size_t)6 * chunk * 1024 + 4096 > ws_size)
    chunk >>= 1;
  const int nchunks = (int)(NE / chunk);

  unsigned short* T0   = (unsigned short*)take((size_t)chunk * 512 * 2);
  unsigned short* T1   = (unsigned short*)take((size_t)chunk * 512 * 2);
  unsigned short* bufR = (unsigned short*)take((size_t)chunk * 512 * 2);
  unsigned short* H3   = (unsigned short*)take((size_t)3 * chunk * 512 * 2);

  float* out   = (float*)d_out;
  float* outRe = out;
  float* outR  = out + (size_t)NE * 512;
  float* outS  = outR + (size_t)3 * NE;
  float* outM  = outS + (size_t)3 * NE;

  weight_prep<<<dim3(256, 12), 256, 0, stream>>>(W0, W1, W2, SW0, SW1, SW2,
                                                 W0t, W1t, W2t, SW0t, SW1t, SW2b);
  relu_cvt_x<<<dim3(NE * 64 / 4 / 256), 256, 0, stream>>>((const float4*)x,
                                                          (ushort4*)Xb);
  build_idx<<<dim3(nchunks, 3), 256, 0, stream>>>(y, prs, (int)chunk,
                                                  idxL, posA, cnts);

  for (int c = 0; c < nchunks; ++c) {
    const long r0 = (long)c * chunk;
    // trunk: Xb -> T0 -> T1 -> (repr fp32, bufR bf16)
    gemmT<<<dim3(chunk / 128, 2, 1), 512, 0, stream>>>(
        Xb + r0 * 64, 0, W0t, 0, b0, 0, nullptr, T0, 0, 64, 512,
        nullptr, 0, nullptr, 0, 0, nullptr, 0, nullptr);
    gemmT<<<dim3(chunk / 128, 2, 1), 512, 0, stream>>>(
        T0, 0, W1t, 0, b1, 0, nullptr, T1, 0, 512, 512,
        nullptr, 0, nullptr, 0, 0, nullptr, 0, nullptr);
    gemmT<<<dim3(chunk / 128, 2, 1), 512, 0, stream>>>(
        T1, 0, W2t, 0, b2, 0, outRe + r0 * 512, bufR, 0, 512, 512,
        nullptr, 0, nullptr, 0, 0, nullptr, 0, nullptr);
    // SW0 batched over p, compacted rows: bufR -> H3[p]
    gemmT<<<dim3(chunk / 128, 2, 3), 512, 0, stream>>>(
        bufR, 0, SW0t, (long)512 * 512, Sb0, 512, nullptr,
        H3, (long)chunk * 512, 512, 512,
        nullptr, 0, nullptr, 0, 0, idxL + r0, NE, cnts + c * 3);
    // SW1 + full fused head on compact rows (Nc=256, y=1)
    gemmT<<<dim3(chunk / 128, 1, 3), 512, 0, stream>>>(
        H3, (long)chunk * 512, SW1t, (long)256 * 512, Sb1, 256, nullptr,
        nullptr, 0, 512, 256,
        SW2b, 256, PB, (long)NE, (int)r0, nullptr, 0, cnts + c * 3);
  }
  head_final<<<dim3(NE / 256, 3), 256, 0, stream>>>(PB, posA, Sb2,
                                                    outR, outS, outM);
}